// Round 10
// baseline (222.590 us; speedup 1.0000x reference)
//
#include <hip/hip_runtime.h>
#include <hip/hip_bf16.h>

typedef __attribute__((ext_vector_type(8))) short short8;
typedef __attribute__((ext_vector_type(4))) float f32x4;

// __float2bfloat16 emits a single HW cvt op on gfx950 — measured faster than
// the 3-op branchless bit-trick (R8: flash 62.3 -> 72.4 us regression).
__device__ __forceinline__ unsigned short f2bf(float f) {
  union { __hip_bfloat16 h; unsigned short u; } cv;
  cv.h = __float2bfloat16(f);
  return cv.u;
}

__device__ __forceinline__ void gld16(const void* g, void* l) {
  __builtin_amdgcn_global_load_lds(
      (const __attribute__((address_space(1))) unsigned int*)g,
      (__attribute__((address_space(3))) unsigned int*)l, 16, 0, 0);
}

__device__ __forceinline__ f32x4 mfma_bf16(short8 a, short8 b, f32x4 c) {
  return __builtin_amdgcn_mfma_f32_16x16x32_bf16(a, b, c, 0, 0, 0);
}

#define QSCALE 0.18033688011112042f  /* 0.125 * log2(e): scores in log2 domain */
#define L2E    1.4426950408889634f

// ---------------------------------------------------------------- prep ----
// One launch: blocks [0,4096) cast X fp32->bf16; blocks [4096,5120) transpose
// weights (first 768: w_attn 64-col strips; last 256: w_proj).
__global__ void prep(const float* __restrict__ x, unsigned short* __restrict__ xbf,
                     const float* __restrict__ wa, unsigned short* __restrict__ da,
                     const float* __restrict__ wp, unsigned short* __restrict__ dp) {
  __shared__ float tile[64][65];
  const int t = threadIdx.x;
  const int bid = blockIdx.x;
  if (bid < 4096) {
    int i = bid * 256 + t;
    float4 v = ((const float4*)x)[i];
    ushort4 o;
    o.x = f2bf(v.x); o.y = f2bf(v.y); o.z = f2bf(v.z); o.w = f2bf(v.w);
    ((ushort4*)xbf)[i] = o;
    return;
  }
  int idx = bid - 4096;          // 0..1023
  const int tr = idx & 15;       // 16 row-strips of 64
  int y = idx >> 4;              // 0..63
  const float* src;
  unsigned short* dst;
  int C;
  if (y < 48) { src = wa; dst = da; C = 3072; }
  else        { src = wp; dst = dp; C = 1024; y -= 48; }
  const int tc = y;  // block-uniform
#pragma unroll
  for (int i = 0; i < 16; ++i) {
    int id2 = t + i * 256;
    int lr = id2 >> 6, lc = id2 & 63;
    tile[lr][lc] = src[(size_t)(tr * 64 + lr) * C + tc * 64 + lc];
  }
  __syncthreads();
#pragma unroll
  for (int i = 0; i < 16; ++i) {
    int id2 = t + i * 256;
    int lr = id2 >> 6, lc = id2 & 63;
    dst[(size_t)(tc * 64 + lr) * 1024 + tr * 64 + lc] = f2bf(tile[lc][lr]);
  }
}

// ---------------------------------------------------------------- GEMM ----
template <int KDIM>
__device__ __forceinline__ void gemm_core(const short* __restrict__ A, const short* __restrict__ Bt,
                                          int mbase, int nbase, short* As, short* Bs,
                                          int wm, int wn, int quad, int l16, int t,
                                          f32x4 (&acc)[4][4]) {
  for (int kt = 0; kt < KDIM / 32; ++kt) {
#pragma unroll
    for (int i = 0; i < 2; ++i) {
      int c = t + i * 256;
      int row = c >> 2, c4 = c & 3;
      gld16(A + (size_t)(mbase + row) * KDIM + kt * 32 + c4 * 8, (char*)As + c * 16);
      gld16(Bt + (size_t)(nbase + row) * KDIM + kt * 32 + c4 * 8, (char*)Bs + c * 16);
    }
    __syncthreads();
    short8 af[4], bf[4];
#pragma unroll
    for (int m = 0; m < 4; ++m)
      af[m] = *(const short8*)((const char*)As + (wm + m * 16 + l16) * 64 + quad * 16);
#pragma unroll
    for (int n = 0; n < 4; ++n)
      bf[n] = *(const short8*)((const char*)Bs + (wn + n * 16 + l16) * 64 + quad * 16);
#pragma unroll
    for (int m = 0; m < 4; ++m)
#pragma unroll
      for (int n = 0; n < 4; ++n)
        acc[m][n] = mfma_bf16(af[m], bf[n], acc[m][n]);
    __syncthreads();
  }
}

// Unified QKV GEMM: grid (32, 24) = 768 blocks (3/CU). nbase<2048 -> Q/K scatter
// (Q pre-scaled by QSCALE for log2-domain flash); nbase>=2048 -> V path with
// LDS-transpose epilogue emitting V' sigma-permuted [bh][d][2048].
__global__ __launch_bounds__(256, 2) void gemm_qkv(
    const short* __restrict__ A, const short* __restrict__ Bt, const float* __restrict__ bias,
    unsigned short* __restrict__ q, unsigned short* __restrict__ k,
    unsigned short* __restrict__ vt) {
  __shared__ __align__(16) char smem[17408];
  short* As = (short*)smem;
  short* Bs = (short*)(smem + 8192);
  unsigned short* vlds = (unsigned short*)smem;  // [64 d][136] permuted s (V epilogue)
  const int t = threadIdx.x;
  const int wave = t >> 6, lane = t & 63;
  const int quad = lane >> 4, l16 = lane & 15;
  const int wm = (wave >> 1) * 64, wn = (wave & 1) * 64;
  const int mbase = blockIdx.x * 128, nbase = blockIdx.y * 128;
  f32x4 acc[4][4];
#pragma unroll
  for (int i = 0; i < 4; ++i)
#pragma unroll
    for (int j = 0; j < 4; ++j) acc[i][j] = (f32x4)0.0f;
  gemm_core<1024>(A, Bt, mbase, nbase, As, Bs, wm, wn, quad, l16, t, acc);

  if (nbase < 2048) {
    // ---- Q/K scatter epilogue ----
#pragma unroll
    for (int n = 0; n < 4; ++n) {
      int col = nbase + wn + n * 16 + l16;      // 0..2047
      float bc = bias[col];
      int which = col >> 10, rem = col & 1023;  // wave-uniform per n
      int h = rem >> 6, d = rem & 63;
      unsigned short* dst = which ? k : q;
      float scale = which ? 1.0f : QSCALE;
#pragma unroll
      for (int m = 0; m < 4; ++m) {
#pragma unroll
        for (int r = 0; r < 4; ++r) {
          int row = mbase + wm + m * 16 + quad * 4 + r;
          int b = row >> 11, s = row & 2047;
          dst[(((size_t)(b * 16 + h)) * 2048 + s) * 64 + d] = f2bf((acc[m][n][r] + bc) * scale);
        }
      }
    }
  } else {
    // ---- V transpose epilogue: V'[bh][d][kt*128 + sigma(s)], sigma(s)=(s&15)*8+(s>>4)
    const int b = mbase >> 11, s0 = mbase & 2047;
    const int vcb = nbase - 2048;  // 0..895, v-column base
    __syncthreads();               // hard fence before vlds reuses the GEMM stage region
#pragma unroll
    for (int half = 0; half < 2; ++half) {
      if (wn == half * 64) {
#pragma unroll
        for (int n = 0; n < 4; ++n) {
          int col_l = n * 16 + l16;  // d 0..63
          float bc = bias[nbase + half * 64 + col_l];
#pragma unroll
          for (int m = 0; m < 4; ++m)
#pragma unroll
            for (int r = 0; r < 4; ++r) {
              int row_l = wm + m * 16 + quad * 4 + r;  // s_local 0..127
              vlds[col_l * 136 + ((row_l & 15) * 8 + (row_l >> 4))] = f2bf(acc[m][n][r] + bc);
            }
        }
      }
      __syncthreads();
      int h = (vcb + half * 64) >> 6;  // head 0..15
      size_t obase = ((size_t)(b * 16 + h)) * 64 * 2048;
#pragma unroll
      for (int i = 0; i < 4; ++i) {
        int c = t + i * 256;
        int d_l = c >> 4, c16 = c & 15;
        short8 v = *(const short8*)&vlds[d_l * 136 + c16 * 8];
        *(short8*)&vt[obase + (size_t)d_l * 2048 + s0 + c16 * 8] = v;
      }
      __syncthreads();
    }
  }
}

// Proj: 64x128 tiles, grid (64,8) = 512 blocks (2/CU) — R8-proven correct+faster.
__global__ __launch_bounds__(256, 2) void gemm_proj(
    const short* __restrict__ A, const short* __restrict__ Bt, const float* __restrict__ bias,
    float* __restrict__ out) {
  __shared__ __align__(16) short As[64 * 32];
  __shared__ __align__(16) short Bs[128 * 32];
  const int t = threadIdx.x;
  const int wave = t >> 6, lane = t & 63;
  const int quad = lane >> 4, l16 = lane & 15;
  const int wm = (wave >> 1) * 32, wn = (wave & 1) * 64;
  const int mbase = blockIdx.x * 64, nbase = blockIdx.y * 128;
  f32x4 acc[2][4];
#pragma unroll
  for (int i = 0; i < 2; ++i)
#pragma unroll
    for (int j = 0; j < 4; ++j) acc[i][j] = (f32x4)0.0f;
  for (int kt = 0; kt < 32; ++kt) {
    {  // A: 64 rows x 4 chunks = 256 chunks, 1/thread
      int row = t >> 2, c4 = t & 3;
      gld16(A + (size_t)(mbase + row) * 1024 + kt * 32 + c4 * 8, (char*)As + t * 16);
    }
#pragma unroll
    for (int i = 0; i < 2; ++i) {  // B: 128 rows x 4 chunks = 512 chunks, 2/thread
      int c = t + i * 256;
      int row = c >> 2, c4 = c & 3;
      gld16(Bt + (size_t)(nbase + row) * 1024 + kt * 32 + c4 * 8, (char*)Bs + c * 16);
    }
    __syncthreads();
    short8 af[2], bf[4];
#pragma unroll
    for (int m = 0; m < 2; ++m)
      af[m] = *(const short8*)((const char*)As + (wm + m * 16 + l16) * 64 + quad * 16);
#pragma unroll
    for (int n = 0; n < 4; ++n)
      bf[n] = *(const short8*)((const char*)Bs + (wn + n * 16 + l16) * 64 + quad * 16);
#pragma unroll
    for (int m = 0; m < 2; ++m)
#pragma unroll
      for (int n = 0; n < 4; ++n)
        acc[m][n] = mfma_bf16(af[m], bf[n], acc[m][n]);
    __syncthreads();
  }
#pragma unroll
  for (int n = 0; n < 4; ++n) {
    int col = nbase + wn + n * 16 + l16;
    float bc = bias[col];
#pragma unroll
    for (int m = 0; m < 2; ++m)
#pragma unroll
      for (int r = 0; r < 4; ++r) {
        int row = mbase + wm + m * 16 + quad * 4 + r;
        out[(size_t)row * 1024 + col] = acc[m][n][r] + bc;
      }
  }
}

// ---------------------------------------------------------------- flash ----
// Br=64 per 128-thread block (2 waves x 32 q-rows, m=2 fragment reuse). Grid
// (32 bh, 32 qt) = 1024 blocks. No online-max (scores bounded, softmax exact);
// log2-domain (Q pre-scaled). P now has its OWN LDS region (no K aliasing):
// 2 barriers/kt instead of 4 — post-S barrier deleted, post-softmax barrier
// replaced by a compiler-only fence (P rows are wave-private; DS is per-wave
// in-order at HW; only compiler reordering — the R6 race — must be blocked).
// LDS 50176 B: K [0,16K), V [16K,32K), P [32K, 32K+17408) -> 3 blocks/CU.
__global__ __launch_bounds__(128, 2) void flash_attn(
    const short* __restrict__ Qg, const short* __restrict__ Kg, const short* __restrict__ Vtg,
    const float* __restrict__ mask, unsigned short* __restrict__ ctx) {
  __shared__ __align__(16) unsigned char smem[50176];
  short* KQsm = (short*)smem;            // K: [128 rows][8 chunks] swizzled; Q: [64][8]
  short* Vsm = (short*)(smem + 16384);   // [64 d][16 chunks] swizzled
  short* Psm = (short*)(smem + 32768);   // [64][136] shorts, dedicated
  const int t = threadIdx.x;  // 0..127
  const int wave = t >> 6, lane = t & 63;
  const int quad = lane >> 4, l16 = lane & 15;
  const int bh = blockIdx.x, b = bh >> 4, h = bh & 15;
  const int qbase = blockIdx.y * 64;
  const size_t bh_off = (size_t)bh * 2048 * 64;

#pragma unroll
  for (int i = 0; i < 4; ++i) {
    int c = t + i * 128;
    int row = c >> 3, col = c & 7;
    gld16(Qg + bh_off + (size_t)(qbase + row) * 64 + (col ^ (row & 7)) * 8,
          (char*)KQsm + c * 16);
  }
  __syncthreads();
  short8 qf[2][2];
#pragma unroll
  for (int m = 0; m < 2; ++m)
#pragma unroll
    for (int ks = 0; ks < 2; ++ks) {
      int row = wave * 32 + m * 16 + l16;
      qf[m][ks] = *(const short8*)((const char*)KQsm +
                                   (row * 8 + ((ks * 4 + quad) ^ (l16 & 7))) * 16);
    }
  __syncthreads();  // all waves done reading Q before K staging reuses region

  f32x4 O[2][4];
  float l_i[2][4];
#pragma unroll
  for (int m = 0; m < 2; ++m)
#pragma unroll
    for (int d = 0; d < 4; ++d) O[m][d] = (f32x4)0.0f;
#pragma unroll
  for (int m = 0; m < 2; ++m)
#pragma unroll
    for (int r = 0; r < 4; ++r) l_i[m][r] = 0.0f;

  for (int kt = 0; kt < 16; ++kt) {
#pragma unroll
    for (int i = 0; i < 8; ++i) {
      int c = t + i * 128;
      int row = c >> 3, col = c & 7;
      gld16(Kg + bh_off + (size_t)(kt * 128 + row) * 64 + (col ^ (row & 7)) * 8,
            (char*)KQsm + c * 16);
    }
#pragma unroll
    for (int i = 0; i < 8; ++i) {
      int c = t + i * 128;
      int d = c >> 4, col = c & 15;
      int gcol = (col & 8) | ((col & 7) ^ (d & 7));
      gld16(Vtg + ((size_t)bh * 64 + d) * 2048 + kt * 128 + gcol * 8,
            (char*)Vsm + c * 16);
    }
    __syncthreads();  // staging complete

    f32x4 sa[2][8];
#pragma unroll
    for (int m = 0; m < 2; ++m)
#pragma unroll
      for (int n = 0; n < 8; ++n) sa[m][n] = (f32x4)0.0f;
#pragma unroll
    for (int ks = 0; ks < 2; ++ks) {
#pragma unroll
      for (int n = 0; n < 8; ++n) {
        int row = n * 16 + l16;
        short8 kf = *(const short8*)((const char*)KQsm +
                                     (row * 8 + ((ks * 4 + quad) ^ (l16 & 7))) * 16);
        sa[0][n] = mfma_bf16(qf[0][ks], kf, sa[0][n]);
        sa[1][n] = mfma_bf16(qf[1][ks], kf, sa[1][n]);
      }
    }
    // no barrier: P lives in its own region, K stays intact until next staging

    float mv[8];
#pragma unroll
    for (int n = 0; n < 8; ++n) mv[n] = mask[b * 2048 + kt * 128 + n * 16 + l16];

#pragma unroll
    for (int m = 0; m < 2; ++m) {
#pragma unroll
      for (int r = 0; r < 4; ++r) {
        float rs = 0.0f;
        short8 p8;
#pragma unroll
        for (int n = 0; n < 8; ++n) {
          float p = __builtin_amdgcn_exp2f(__builtin_fmaf(mv[n], L2E, sa[m][n][r]));
          rs += p;
          p8[n] = (short)f2bf(p);
        }
        *(short8*)((char*)Psm + (wave * 32 + m * 16 + quad * 4 + r) * 272 + l16 * 16) = p8;
        l_i[m][r] += rs;
      }
    }
    // compiler-only fence: forbid reordering P reads before P writes (R6 race).
    // HW DS ops are per-wave in-order; P rows are wave-private.
    asm volatile("" ::: "memory");

#pragma unroll
    for (int ks = 0; ks < 4; ++ks) {
      short8 pf[2];
#pragma unroll
      for (int m = 0; m < 2; ++m)
        pf[m] = *(const short8*)((const char*)Psm +
                                 (wave * 32 + m * 16 + l16) * 272 + ks * 64 + quad * 16);
#pragma unroll
      for (int db = 0; db < 4; ++db) {
        int d = db * 16 + l16;
        int u = ks * 4 + quad;
        int c = (u & 8) | ((u & 7) ^ (d & 7));
        short8 vf = *(const short8*)((const char*)Vsm + d * 256 + c * 16);
        O[0][db] = mfma_bf16(pf[0], vf, O[0][db]);
        O[1][db] = mfma_bf16(pf[1], vf, O[1][db]);
      }
    }
    __syncthreads();  // K & V reads done block-wide before next staging
  }

#pragma unroll
  for (int m = 0; m < 2; ++m) {
#pragma unroll
    for (int r = 0; r < 4; ++r) {
      float l = l_i[m][r];
      l += __shfl_xor(l, 1);
      l += __shfl_xor(l, 2);
      l += __shfl_xor(l, 4);
      l += __shfl_xor(l, 8);
      float inv = 1.0f / l;
      int s = qbase + wave * 32 + m * 16 + quad * 4 + r;
      size_t o = ((size_t)b * 2048 + s) * 1024 + h * 64;
#pragma unroll
      for (int db = 0; db < 4; ++db)
        ctx[o + db * 16 + l16] = f2bf(O[m][db][r] * inv);
    }
  }
}

// ---------------------------------------------------------------- launch ----
extern "C" void kernel_launch(void* const* d_in, const int* in_sizes, int n_in,
                              void* d_out, int out_size, void* d_ws, size_t ws_size,
                              hipStream_t stream) {
  const float* x      = (const float*)d_in[0];
  const float* mask   = (const float*)d_in[1];
  const float* w_attn = (const float*)d_in[2];
  const float* b_attn = (const float*)d_in[3];
  const float* w_proj = (const float*)d_in[4];
  const float* b_proj = (const float*)d_in[5];
  float* out = (float*)d_out;

  char* ws = (char*)d_ws;
  const size_t MB = 1024 * 1024;
  short*          Xbf    = (short*)(ws);                     // 8 MB, reused as ctx
  short*          Wqkv_t = (short*)(ws + 8 * MB);            // 6 MB
  short*          Wprj_t = (short*)(ws + 14 * MB);           // 2 MB
  unsigned short* Qb     = (unsigned short*)(ws + 16 * MB);  // 8 MB
  unsigned short* Kb     = (unsigned short*)(ws + 24 * MB);  // 8 MB
  unsigned short* Vtb    = (unsigned short*)(ws + 32 * MB);  // 8 MB
  unsigned short* ctx    = (unsigned short*)Xbf;

  prep<<<5120, 256, 0, stream>>>(x, (unsigned short*)Xbf,
                                 w_attn, (unsigned short*)Wqkv_t,
                                 w_proj, (unsigned short*)Wprj_t);
  gemm_qkv<<<dim3(32, 24), 256, 0, stream>>>(Xbf, Wqkv_t, b_attn, Qb, Kb, Vtb);
  flash_attn<<<dim3(32, 32), 128, 0, stream>>>((const short*)Qb, (const short*)Kb,
                                               (const short*)Vtb, mask, ctx);
  gemm_proj<<<dim3(64, 8), 256, 0, stream>>>((const short*)ctx, Wprj_t, b_proj, out);
}

// Round 11
// 191.263 us; speedup vs baseline: 1.1638x; 1.1638x over previous
//
#include <hip/hip_runtime.h>
#include <hip/hip_bf16.h>

typedef __attribute__((ext_vector_type(8))) short short8;
typedef __attribute__((ext_vector_type(4))) float f32x4;

// __float2bfloat16 emits a single HW cvt op on gfx950 (R8: bit-trick regressed).
__device__ __forceinline__ unsigned short f2bf(float f) {
  union { __hip_bfloat16 h; unsigned short u; } cv;
  cv.h = __float2bfloat16(f);
  return cv.u;
}

__device__ __forceinline__ void gld16(const void* g, void* l) {
  __builtin_amdgcn_global_load_lds(
      (const __attribute__((address_space(1))) unsigned int*)g,
      (__attribute__((address_space(3))) unsigned int*)l, 16, 0, 0);
}

__device__ __forceinline__ f32x4 mfma_bf16(short8 a, short8 b, f32x4 c) {
  return __builtin_amdgcn_mfma_f32_16x16x32_bf16(a, b, c, 0, 0, 0);
}

#define QSCALE 0.18033688011112042f  /* 0.125 * log2(e): scores in log2 domain */
#define L2E    1.4426950408889634f

// ---------------------------------------------------------------- prep ----
// One launch: blocks [0,4096) cast X fp32->bf16; blocks [4096,5120) transpose
// weights (first 768: w_attn 64-col strips; last 256: w_proj).
__global__ void prep(const float* __restrict__ x, unsigned short* __restrict__ xbf,
                     const float* __restrict__ wa, unsigned short* __restrict__ da,
                     const float* __restrict__ wp, unsigned short* __restrict__ dp) {
  __shared__ float tile[64][65];
  const int t = threadIdx.x;
  const int bid = blockIdx.x;
  if (bid < 4096) {
    int i = bid * 256 + t;
    float4 v = ((const float4*)x)[i];
    ushort4 o;
    o.x = f2bf(v.x); o.y = f2bf(v.y); o.z = f2bf(v.z); o.w = f2bf(v.w);
    ((ushort4*)xbf)[i] = o;
    return;
  }
  int idx = bid - 4096;          // 0..1023
  const int tr = idx & 15;       // 16 row-strips of 64
  int y = idx >> 4;              // 0..63
  const float* src;
  unsigned short* dst;
  int C;
  if (y < 48) { src = wa; dst = da; C = 3072; }
  else        { src = wp; dst = dp; C = 1024; y -= 48; }
  const int tc = y;  // block-uniform
#pragma unroll
  for (int i = 0; i < 16; ++i) {
    int id2 = t + i * 256;
    int lr = id2 >> 6, lc = id2 & 63;
    tile[lr][lc] = src[(size_t)(tr * 64 + lr) * C + tc * 64 + lc];
  }
  __syncthreads();
#pragma unroll
  for (int i = 0; i < 16; ++i) {
    int id2 = t + i * 256;
    int lr = id2 >> 6, lc = id2 & 63;
    dst[(size_t)(tc * 64 + lr) * 1024 + tr * 64 + lc] = f2bf(tile[lc][lr]);
  }
}

// ---------------------------------------------------------------- GEMM ----
template <int KDIM>
__device__ __forceinline__ void gemm_core(const short* __restrict__ A, const short* __restrict__ Bt,
                                          int mbase, int nbase, short* As, short* Bs,
                                          int wm, int wn, int quad, int l16, int t,
                                          f32x4 (&acc)[4][4]) {
  for (int kt = 0; kt < KDIM / 32; ++kt) {
#pragma unroll
    for (int i = 0; i < 2; ++i) {
      int c = t + i * 256;
      int row = c >> 2, c4 = c & 3;
      gld16(A + (size_t)(mbase + row) * KDIM + kt * 32 + c4 * 8, (char*)As + c * 16);
      gld16(Bt + (size_t)(nbase + row) * KDIM + kt * 32 + c4 * 8, (char*)Bs + c * 16);
    }
    __syncthreads();
    short8 af[4], bf[4];
#pragma unroll
    for (int m = 0; m < 4; ++m)
      af[m] = *(const short8*)((const char*)As + (wm + m * 16 + l16) * 64 + quad * 16);
#pragma unroll
    for (int n = 0; n < 4; ++n)
      bf[n] = *(const short8*)((const char*)Bs + (wn + n * 16 + l16) * 64 + quad * 16);
#pragma unroll
    for (int m = 0; m < 4; ++m)
#pragma unroll
      for (int n = 0; n < 4; ++n)
        acc[m][n] = mfma_bf16(af[m], bf[n], acc[m][n]);
    __syncthreads();
  }
}

// Unified QKV GEMM: grid (32, 24) = 768 blocks (3/CU). nbase<2048 -> Q/K scatter
// (Q pre-scaled by QSCALE for log2-domain flash); nbase>=2048 -> V path with
// LDS-transpose epilogue emitting V' sigma-permuted [bh][d][2048].
__global__ __launch_bounds__(256, 2) void gemm_qkv(
    const short* __restrict__ A, const short* __restrict__ Bt, const float* __restrict__ bias,
    unsigned short* __restrict__ q, unsigned short* __restrict__ k,
    unsigned short* __restrict__ vt) {
  __shared__ __align__(16) char smem[17408];
  short* As = (short*)smem;
  short* Bs = (short*)(smem + 8192);
  unsigned short* vlds = (unsigned short*)smem;  // [64 d][136] permuted s (V epilogue)
  const int t = threadIdx.x;
  const int wave = t >> 6, lane = t & 63;
  const int quad = lane >> 4, l16 = lane & 15;
  const int wm = (wave >> 1) * 64, wn = (wave & 1) * 64;
  const int mbase = blockIdx.x * 128, nbase = blockIdx.y * 128;
  f32x4 acc[4][4];
#pragma unroll
  for (int i = 0; i < 4; ++i)
#pragma unroll
    for (int j = 0; j < 4; ++j) acc[i][j] = (f32x4)0.0f;
  gemm_core<1024>(A, Bt, mbase, nbase, As, Bs, wm, wn, quad, l16, t, acc);

  if (nbase < 2048) {
    // ---- Q/K scatter epilogue ----
#pragma unroll
    for (int n = 0; n < 4; ++n) {
      int col = nbase + wn + n * 16 + l16;      // 0..2047
      float bc = bias[col];
      int which = col >> 10, rem = col & 1023;  // wave-uniform per n
      int h = rem >> 6, d = rem & 63;
      unsigned short* dst = which ? k : q;
      float scale = which ? 1.0f : QSCALE;
#pragma unroll
      for (int m = 0; m < 4; ++m) {
#pragma unroll
        for (int r = 0; r < 4; ++r) {
          int row = mbase + wm + m * 16 + quad * 4 + r;
          int b = row >> 11, s = row & 2047;
          dst[(((size_t)(b * 16 + h)) * 2048 + s) * 64 + d] = f2bf((acc[m][n][r] + bc) * scale);
        }
      }
    }
  } else {
    // ---- V transpose epilogue: V'[bh][d][kt*128 + sigma(s)], sigma(s)=(s&15)*8+(s>>4)
    const int b = mbase >> 11, s0 = mbase & 2047;
    const int vcb = nbase - 2048;  // 0..895, v-column base
    __syncthreads();               // hard fence before vlds reuses the GEMM stage region
#pragma unroll
    for (int half = 0; half < 2; ++half) {
      if (wn == half * 64) {
#pragma unroll
        for (int n = 0; n < 4; ++n) {
          int col_l = n * 16 + l16;  // d 0..63
          float bc = bias[nbase + half * 64 + col_l];
#pragma unroll
          for (int m = 0; m < 4; ++m)
#pragma unroll
            for (int r = 0; r < 4; ++r) {
              int row_l = wm + m * 16 + quad * 4 + r;  // s_local 0..127
              vlds[col_l * 136 + ((row_l & 15) * 8 + (row_l >> 4))] = f2bf(acc[m][n][r] + bc);
            }
        }
      }
      __syncthreads();
      int h = (vcb + half * 64) >> 6;  // head 0..15
      size_t obase = ((size_t)(b * 16 + h)) * 64 * 2048;
#pragma unroll
      for (int i = 0; i < 4; ++i) {
        int c = t + i * 256;
        int d_l = c >> 4, c16 = c & 15;
        short8 v = *(const short8*)&vlds[d_l * 136 + c16 * 8];
        *(short8*)&vt[obase + (size_t)d_l * 2048 + s0 + c16 * 8] = v;
      }
      __syncthreads();
    }
  }
}

// Proj: 64x128 tiles, grid (64,8) = 512 blocks (2/CU) — R8-proven correct+faster.
__global__ __launch_bounds__(256, 2) void gemm_proj(
    const short* __restrict__ A, const short* __restrict__ Bt, const float* __restrict__ bias,
    float* __restrict__ out) {
  __shared__ __align__(16) short As[64 * 32];
  __shared__ __align__(16) short Bs[128 * 32];
  const int t = threadIdx.x;
  const int wave = t >> 6, lane = t & 63;
  const int quad = lane >> 4, l16 = lane & 15;
  const int wm = (wave >> 1) * 32, wn = (wave & 1) * 64;
  const int mbase = blockIdx.x * 64, nbase = blockIdx.y * 128;
  f32x4 acc[2][4];
#pragma unroll
  for (int i = 0; i < 2; ++i)
#pragma unroll
    for (int j = 0; j < 4; ++j) acc[i][j] = (f32x4)0.0f;
  for (int kt = 0; kt < 32; ++kt) {
    {  // A: 64 rows x 4 chunks = 256 chunks, 1/thread
      int row = t >> 2, c4 = t & 3;
      gld16(A + (size_t)(mbase + row) * 1024 + kt * 32 + c4 * 8, (char*)As + t * 16);
    }
#pragma unroll
    for (int i = 0; i < 2; ++i) {  // B: 128 rows x 4 chunks = 512 chunks, 2/thread
      int c = t + i * 256;
      int row = c >> 2, c4 = c & 3;
      gld16(Bt + (size_t)(nbase + row) * 1024 + kt * 32 + c4 * 8, (char*)Bs + c * 16);
    }
    __syncthreads();
    short8 af[2], bf[4];
#pragma unroll
    for (int m = 0; m < 2; ++m)
      af[m] = *(const short8*)((const char*)As + (wm + m * 16 + l16) * 64 + quad * 16);
#pragma unroll
    for (int n = 0; n < 4; ++n)
      bf[n] = *(const short8*)((const char*)Bs + (wn + n * 16 + l16) * 64 + quad * 16);
#pragma unroll
    for (int m = 0; m < 2; ++m)
#pragma unroll
      for (int n = 0; n < 4; ++n)
        acc[m][n] = mfma_bf16(af[m], bf[n], acc[m][n]);
    __syncthreads();
  }
#pragma unroll
  for (int n = 0; n < 4; ++n) {
    int col = nbase + wn + n * 16 + l16;
    float bc = bias[col];
#pragma unroll
    for (int m = 0; m < 2; ++m)
#pragma unroll
      for (int r = 0; r < 4; ++r) {
        int row = mbase + wm + m * 16 + quad * 4 + r;
        out[(size_t)row * 1024 + col] = acc[m][n][r] + bc;
      }
  }
}

// ---------------------------------------------------------------- flash ----
// Br=64 per 128-thread block (2 waves x 32 q-rows). Grid (32 bh, 32 qt).
// LDS = 40960 B EXACTLY (160KB/4 -> 4 blocks/CU; R10 measured 50176 B -> 2
// blocks/CU cliff): K [0,16K), V [16K,32K), P-half [32K,40960) = 32 rows x
// 256 B XOR-swizzled. P halved by m (softmax->PV per m); rows wave-private so
// only a compiler fence (R10-proven) orders write->read. V-frags cached in
// registers at m=0 (keeps DS reads at 48/wave-kt). 2 barriers/kt (was 4).
__global__ __launch_bounds__(128, 2) void flash_attn(
    const short* __restrict__ Qg, const short* __restrict__ Kg, const short* __restrict__ Vtg,
    const float* __restrict__ mask, unsigned short* __restrict__ ctx) {
  __shared__ __align__(16) unsigned char smem[40960];
  short* KQsm = (short*)smem;            // K: [128 rows][8 chunks] swizzled; Q: [64][8]
  short* Vsm = (short*)(smem + 16384);   // [64 d][16 chunks] swizzled
  short* Psm = (short*)(smem + 32768);   // [32 rows][16 chunks] swizzled, m-half
  const int t = threadIdx.x;  // 0..127
  const int wave = t >> 6, lane = t & 63;
  const int quad = lane >> 4, l16 = lane & 15;
  const int bh = blockIdx.x, b = bh >> 4, h = bh & 15;
  const int qbase = blockIdx.y * 64;
  const size_t bh_off = (size_t)bh * 2048 * 64;

#pragma unroll
  for (int i = 0; i < 4; ++i) {
    int c = t + i * 128;
    int row = c >> 3, col = c & 7;
    gld16(Qg + bh_off + (size_t)(qbase + row) * 64 + (col ^ (row & 7)) * 8,
          (char*)KQsm + c * 16);
  }
  __syncthreads();
  short8 qf[2][2];
#pragma unroll
  for (int m = 0; m < 2; ++m)
#pragma unroll
    for (int ks = 0; ks < 2; ++ks) {
      int row = wave * 32 + m * 16 + l16;
      qf[m][ks] = *(const short8*)((const char*)KQsm +
                                   (row * 8 + ((ks * 4 + quad) ^ (l16 & 7))) * 16);
    }
  __syncthreads();  // all waves done reading Q before K staging reuses region

  f32x4 O[2][4];
  float l_i[2][4];
#pragma unroll
  for (int m = 0; m < 2; ++m)
#pragma unroll
    for (int d = 0; d < 4; ++d) O[m][d] = (f32x4)0.0f;
#pragma unroll
  for (int m = 0; m < 2; ++m)
#pragma unroll
    for (int r = 0; r < 4; ++r) l_i[m][r] = 0.0f;

  for (int kt = 0; kt < 16; ++kt) {
#pragma unroll
    for (int i = 0; i < 8; ++i) {
      int c = t + i * 128;
      int row = c >> 3, col = c & 7;
      gld16(Kg + bh_off + (size_t)(kt * 128 + row) * 64 + (col ^ (row & 7)) * 8,
            (char*)KQsm + c * 16);
    }
#pragma unroll
    for (int i = 0; i < 8; ++i) {
      int c = t + i * 128;
      int d = c >> 4, col = c & 15;
      int gcol = (col & 8) | ((col & 7) ^ (d & 7));
      gld16(Vtg + ((size_t)bh * 64 + d) * 2048 + kt * 128 + gcol * 8,
            (char*)Vsm + c * 16);
    }
    __syncthreads();  // staging complete

    // S = Q @ K^T (log2 domain), both m-tiles per kf read
    f32x4 sa[2][8];
#pragma unroll
    for (int m = 0; m < 2; ++m)
#pragma unroll
      for (int n = 0; n < 8; ++n) sa[m][n] = (f32x4)0.0f;
#pragma unroll
    for (int ks = 0; ks < 2; ++ks) {
#pragma unroll
      for (int n = 0; n < 8; ++n) {
        int row = n * 16 + l16;
        short8 kf = *(const short8*)((const char*)KQsm +
                                     (row * 8 + ((ks * 4 + quad) ^ (l16 & 7))) * 16);
        sa[0][n] = mfma_bf16(qf[0][ks], kf, sa[0][n]);
        sa[1][n] = mfma_bf16(qf[1][ks], kf, sa[1][n]);
      }
    }
    // no barrier: P has its own region; K stays intact until next staging

    float mv[8];
#pragma unroll
    for (int n = 0; n < 8; ++n) mv[n] = mask[b * 2048 + kt * 128 + n * 16 + l16];

    short8 vfc[4][4];  // V-frag cache, filled at m=0, reused at m=1
#pragma unroll
    for (int m = 0; m < 2; ++m) {
      // softmax m-half -> P (one b128/row, XOR-swizzled stride-256 layout)
#pragma unroll
      for (int r = 0; r < 4; ++r) {
        float rs = 0.0f;
        short8 p8;
#pragma unroll
        for (int n = 0; n < 8; ++n) {
          float p = __builtin_amdgcn_exp2f(__builtin_fmaf(mv[n], L2E, sa[m][n][r]));
          rs += p;
          p8[n] = (short)f2bf(p);
        }
        int prow = wave * 16 + quad * 4 + r;  // 0..31, wave-private half
        *(short8*)((char*)Psm + prow * 256 + ((l16 ^ (prow & 7)) * 16)) = p8;
        l_i[m][r] += rs;
      }
      // compiler-only fence: P rows wave-private, HW DS per-wave in-order (R10-proven)
      asm volatile("" ::: "memory");

      // O[m] += P @ V'
#pragma unroll
      for (int ks = 0; ks < 4; ++ks) {
        int prow = wave * 16 + l16;
        short8 pf = *(const short8*)((const char*)Psm +
                                     prow * 256 + (((ks * 4 + quad) ^ (l16 & 7)) * 16));
#pragma unroll
        for (int db = 0; db < 4; ++db) {
          if (m == 0) {
            int d = db * 16 + l16;
            int u = ks * 4 + quad;
            int c = (u & 8) | ((u & 7) ^ (d & 7));
            vfc[ks][db] = *(const short8*)((const char*)Vsm + d * 256 + c * 16);
          }
          O[m][db] = mfma_bf16(pf, vfc[ks][db], O[m][db]);
        }
      }
      // fence: m=1 P-writes must not hoist above m=0 P-reads
      asm volatile("" ::: "memory");
    }
    __syncthreads();  // K & V reads done block-wide before next staging
  }

#pragma unroll
  for (int m = 0; m < 2; ++m) {
#pragma unroll
    for (int r = 0; r < 4; ++r) {
      float l = l_i[m][r];
      l += __shfl_xor(l, 1);
      l += __shfl_xor(l, 2);
      l += __shfl_xor(l, 4);
      l += __shfl_xor(l, 8);
      float inv = 1.0f / l;
      int s = qbase + wave * 32 + m * 16 + quad * 4 + r;
      size_t o = ((size_t)b * 2048 + s) * 1024 + h * 64;
#pragma unroll
      for (int db = 0; db < 4; ++db)
        ctx[o + db * 16 + l16] = f2bf(O[m][db][r] * inv);
    }
  }
}

// ---------------------------------------------------------------- launch ----
extern "C" void kernel_launch(void* const* d_in, const int* in_sizes, int n_in,
                              void* d_out, int out_size, void* d_ws, size_t ws_size,
                              hipStream_t stream) {
  const float* x      = (const float*)d_in[0];
  const float* mask   = (const float*)d_in[1];
  const float* w_attn = (const float*)d_in[2];
  const float* b_attn = (const float*)d_in[3];
  const float* w_proj = (const float*)d_in[4];
  const float* b_proj = (const float*)d_in[5];
  float* out = (float*)d_out;

  char* ws = (char*)d_ws;
  const size_t MB = 1024 * 1024;
  short*          Xbf    = (short*)(ws);                     // 8 MB, reused as ctx
  short*          Wqkv_t = (short*)(ws + 8 * MB);            // 6 MB
  short*          Wprj_t = (short*)(ws + 14 * MB);           // 2 MB
  unsigned short* Qb     = (unsigned short*)(ws + 16 * MB);  // 8 MB
  unsigned short* Kb     = (unsigned short*)(ws + 24 * MB);  // 8 MB
  unsigned short* Vtb    = (unsigned short*)(ws + 32 * MB);  // 8 MB
  unsigned short* ctx    = (unsigned short*)Xbf;

  prep<<<5120, 256, 0, stream>>>(x, (unsigned short*)Xbf,
                                 w_attn, (unsigned short*)Wqkv_t,
                                 w_proj, (unsigned short*)Wprj_t);
  gemm_qkv<<<dim3(32, 24), 256, 0, stream>>>(Xbf, Wqkv_t, b_attn, Qb, Kb, Vtb);
  flash_attn<<<dim3(32, 32), 128, 0, stream>>>((const short*)Qb, (const short*)Kb,
                                               (const short*)Vtb, mask, ctx);
  gemm_proj<<<dim3(64, 8), 256, 0, stream>>>((const short*)ctx, Wprj_t, b_proj, out);
}